// Round 8
// baseline (238.164 us; speedup 1.0000x reference)
//
#include <hip/hip_runtime.h>
#include <math.h>

#define B 256
#define S 50
#define D 32
#define V 10000
#define VPAD 10240
#define KK 16
#define HH 64
#define LL 2
#define UU 32
#define TT 30          // trigger_seq_length
#define NROWS (B*S)    // 12800
#define NORMC 0.01f
#define NSLICE 20
#define SLICE_V 512    // VPAD / NSLICE
#define NTILES 32      // SLICE_V / 16
#define VQ_RB 128      // rows per k_vq block
#define NRG (NROWS / VQ_RB)   // 100

typedef __attribute__((ext_vector_type(8))) short bf16x8;
typedef __attribute__((ext_vector_type(4))) float f32x4;

__device__ __forceinline__ float sigmoidf_(float x) { return 1.0f / (1.0f + expf(-x)); }

__device__ __forceinline__ unsigned short f2bf(float x) {
    union { float f; unsigned int u; } a; a.f = x;
    unsigned int u = a.u;
    return (unsigned short)((u + 0x7FFFu + ((u >> 16) & 1u)) >> 16);  // RNE, inputs finite
}
__device__ __forceinline__ float bf2f(unsigned short h) {
    union { unsigned int u; float f; } a; a.u = ((unsigned int)h) << 16; return a.f;
}

__device__ __forceinline__ void gld16(void* lds, const void* g) {
    __builtin_amdgcn_global_load_lds(
        (const __attribute__((address_space(1))) unsigned int*)g,
        (__attribute__((address_space(3))) unsigned int*)lds, 16, 0, 0);
}

// ---------------- prep: split embd fp32 -> (hi,lo) bf16, pad to VPAD (zeros, tn=+inf);
// tnorm; zero loss + ticket. (Q split in-register inside k_vq.)
__global__ __launch_bounds__(256) void k_prep(const float* __restrict__ embd,
                                              unsigned short* __restrict__ Eh, unsigned short* __restrict__ El,
                                              float* __restrict__ tn, float* __restrict__ loss_sum,
                                              unsigned int* __restrict__ cnt) {
    int gid = blockIdx.x * 256 + threadIdx.x;
    if (gid == 0) loss_sum[0] = 0.f;
    if (gid == 1) cnt[0] = 0u;
    if (gid >= VPAD * 4) return;
    int item = gid >> 2, qd = gid & 3;
    unsigned short* dh = Eh + (size_t)item * D + qd * 8;
    unsigned short* dl = El + (size_t)item * D + qd * 8;
    if (item >= V) {
        unsigned short z[8] = {0, 0, 0, 0, 0, 0, 0, 0};
        *(uint4*)dh = *(const uint4*)z;
        *(uint4*)dl = *(const uint4*)z;
        if (qd == 0) tn[item] = INFINITY;
        return;
    }
    const float* src = embd + (size_t)item * D + qd * 8;
    float4 x0 = *(const float4*)(src);
    float4 x1 = *(const float4*)(src + 4);
    float xs[8] = {x0.x, x0.y, x0.z, x0.w, x1.x, x1.y, x1.z, x1.w};
    unsigned short hv[8], lv[8];
    float ss = 0.f;
#pragma unroll
    for (int i = 0; i < 8; i++) {
        float x = xs[i];
        ss = fmaf(x, x, ss);
        unsigned short h = f2bf(x);
        hv[i] = h;
        lv[i] = f2bf(x - bf2f(h));
    }
    *(uint4*)dh = *(const uint4*)hv;
    *(uint4*)dl = *(const uint4*)lv;
    ss += __shfl_xor(ss, 1);
    ss += __shfl_xor(ss, 2);
    if (qd == 0) tn[item] = 0.5f * ss;
}

// ---------------- VQ argmin v4: whole-slice LDS, ONE barrier per block ----------------
// 2000 blocks (slice-major: slice=bid/100, rg=bid%100) x 256 thr = 4 waves.
// Stage 512 codes (64KB: EhL+ElL, XOR-swizzled) once, single barrier, then each wave:
// 32 rows x 32 tiles x 6 MFMA with zero further syncs. tn pinned in 32 VGPRs.
__global__ __launch_bounds__(256) void k_vq(const float* __restrict__ z1,
                                            const short* __restrict__ Eh, const short* __restrict__ El,
                                            const float* __restrict__ tn,
                                            float2* __restrict__ pbsv) {
    __shared__ __attribute__((aligned(16))) short EhL[SLICE_V * 32];  // 32 KB
    __shared__ __attribute__((aligned(16))) short ElL[SLICE_V * 32];  // 32 KB -> 64 KB total
    const int tid = threadIdx.x;
    const int wave = tid >> 6, lane = tid & 63;
    const int slice = blockIdx.x / NRG, rg = blockIdx.x % NRG;
    const int row0 = rg * VQ_RB;
    const int quad = lane >> 4, c15 = lane & 15;
    const int swz = quad ^ ((c15 >> 1) & 3);            // reader swizzle (16B units)
    const int vbeg = slice * SLICE_V;
    // stage: 4096 16B-units total (Eh+El), 8+8 per lane, swizzled within 64B code rows
    {
#pragma unroll
        for (int i = 0; i < 8; i++) {
            int c = wave * 512 + i * 64 + lane;          // 16B-unit index 0..2047
            int code = c >> 2;
            int q = (c & 3) ^ ((c >> 3) & 3);
            int srcOff = (vbeg + code) * 32 + q * 8;     // shorts
            int dstOff = (wave * 512 + i * 64) * 8;      // shorts (HW adds lane*16B)
            gld16(EhL + dstOff, Eh + srcOff);
            gld16(ElL + dstOff, El + srcOff);
        }
    }
    // A fragments: negate+split z1 in-register (2 rowtiles per wave)
    const int ar0 = row0 + wave * 32 + c15;
    bf16x8 ah0, al0, ah1, al1;
#pragma unroll
    for (int rt = 0; rt < 2; rt++) {
        const float* qp = z1 + (size_t)(ar0 + rt * 16) * 32 + quad * 8;
        float4 x0 = *(const float4*)qp;
        float4 x1v = *(const float4*)(qp + 4);
        float xs[8] = {x0.x, x0.y, x0.z, x0.w, x1v.x, x1v.y, x1v.z, x1v.w};
        short hv[8], lv[8];
#pragma unroll
        for (int i = 0; i < 8; i++) {
            float x = -xs[i];
            unsigned short h = f2bf(x);
            hv[i] = (short)h;
            lv[i] = (short)f2bf(x - bf2f(h));
        }
        if (rt == 0) { ah0 = *(const bf16x8*)hv; al0 = *(const bf16x8*)lv; }
        else         { ah1 = *(const bf16x8*)hv; al1 = *(const bf16x8*)lv; }
    }
    // tn pinned in registers (quads redundant -> L1 broadcast)
    float tnr[NTILES];
#pragma unroll
    for (int t = 0; t < NTILES; t++) tnr[t] = tn[vbeg + t * 16 + c15];
    float best0[4], best1[4]; int bv0[4], bv1[4];
#pragma unroll
    for (int i = 0; i < 4; i++) {
        best0[i] = INFINITY; best1[i] = INFINITY;
        bv0[i] = 0x7fffffff; bv1[i] = 0x7fffffff;
    }
    __syncthreads();   // the only barrier: staged slice visible
#pragma unroll
    for (int t = 0; t < NTILES; t++) {
        const int code = t * 16 + c15;
        const int boff = code * 32 + swz * 8;            // shorts
        bf16x8 bh = *(const bf16x8*)(EhL + boff);
        bf16x8 bl = *(const bf16x8*)(ElL + boff);
        const float tnv = tnr[t];
        f32x4 acc0 = {tnv, tnv, tnv, tnv};
        f32x4 acc1 = {tnv, tnv, tnv, tnv};
        acc0 = __builtin_amdgcn_mfma_f32_16x16x32_bf16(ah0, bh, acc0, 0, 0, 0);
        acc1 = __builtin_amdgcn_mfma_f32_16x16x32_bf16(ah1, bh, acc1, 0, 0, 0);
        acc0 = __builtin_amdgcn_mfma_f32_16x16x32_bf16(al0, bh, acc0, 0, 0, 0);
        acc1 = __builtin_amdgcn_mfma_f32_16x16x32_bf16(al1, bh, acc1, 0, 0, 0);
        acc0 = __builtin_amdgcn_mfma_f32_16x16x32_bf16(ah0, bl, acc0, 0, 0, 0);
        acc1 = __builtin_amdgcn_mfma_f32_16x16x32_bf16(ah1, bl, acc1, 0, 0, 0);
        const int v = vbeg + code;                        // pad codes carry tn=+inf
#pragma unroll
        for (int i = 0; i < 4; i++) {
            float s0 = acc0[i];
            if (s0 < best0[i]) { best0[i] = s0; bv0[i] = v; }   // ascending t => lowest v on ties
            float s1 = acc1[i];
            if (s1 < best1[i]) { best1[i] = s1; bv1[i] = v; }
        }
    }
    // reduce across the 16 col-lanes (lane bits 0..3); rows (quad,i) preserved
#pragma unroll
    for (int m = 1; m <= 8; m <<= 1) {
#pragma unroll
        for (int i = 0; i < 4; i++) {
            float os = __shfl_xor(best0[i], m); int ov = __shfl_xor(bv0[i], m);
            if (os < best0[i] || (os == best0[i] && ov < bv0[i])) { best0[i] = os; bv0[i] = ov; }
            os = __shfl_xor(best1[i], m); ov = __shfl_xor(bv1[i], m);
            if (os < best1[i] || (os == best1[i] && ov < bv1[i])) { best1[i] = os; bv1[i] = ov; }
        }
    }
    if (c15 == 0) {
#pragma unroll
        for (int i = 0; i < 4; i++) {
            int r0 = row0 + wave * 32 + quad * 4 + i;
            float2 p0; p0.x = best0[i]; p0.y = __int_as_float(bv0[i]);
            pbsv[(size_t)r0 * NSLICE + slice] = p0;
            int r1 = r0 + 16;
            float2 p1; p1.x = best1[i]; p1.y = __int_as_float(bv1[i]);
            pbsv[(size_t)r1 * NSLICE + slice] = p1;
        }
    }
}

// ---------------- fused: merge + gather + loss + decoder + 2xGRU + MLPs + wgen + apply ----
// One block per sample (256 blocks x 256 thr). (Round-6 version, measured 44 us.)
__global__ __launch_bounds__(256) void k_fused(
        const float* __restrict__ x1, const float* __restrict__ z2,
        const float* __restrict__ embd, const float2* __restrict__ pbsv,
        const float* __restrict__ dw1, const float* __restrict__ db1,
        const float* __restrict__ dw2, const float* __restrict__ db2,
        const float* __restrict__ i_wih, const float* __restrict__ i_whh,
        const float* __restrict__ i_bih, const float* __restrict__ i_bhh,
        const float* __restrict__ c_wih, const float* __restrict__ c_whh,
        const float* __restrict__ c_bih, const float* __restrict__ c_bhh,
        const float* __restrict__ im_w1, const float* __restrict__ im_b1,
        const float* __restrict__ im_w2, const float* __restrict__ im_b2,
        const float* __restrict__ cm_w1, const float* __restrict__ cm_b1,
        const float* __restrict__ cm_w2, const float* __restrict__ cm_b2,
        const float* __restrict__ hw1, const float* __restrict__ hb1,
        const float* __restrict__ hw2, const float* __restrict__ hb2,
        const float* __restrict__ lin_w, const float* __restrict__ lin_b,
        const float* __restrict__ lout_w, const float* __restrict__ lout_b,
        float* __restrict__ loss_sum, unsigned int* __restrict__ cnt,
        float* __restrict__ out) {
    __shared__ float zeL[50][33];
    __shared__ float dw1L[2048], dw2L[2048];
    __shared__ float db1L[64], db2L[32];
    __shared__ __attribute__((aligned(16))) float xsi[TT + 1][32];
    __shared__ float gii[TT + 1][96], gic[TT + 1][96];
    __shared__ float aL[TT + 1][65];
    __shared__ __attribute__((aligned(16))) float hI[2][32], hC[2][32];
    __shared__ float ghI[96], ghC[96];
    __shared__ float afL[2][32];
    __shared__ float z1fL[32], z2fL[32];
    __shared__ float wW[512];
    __shared__ float t1s[16], t2s[16], ocs[32];
    __shared__ int   vidL[50];
    __shared__ float lossRed[4];
    const int tid = threadIdx.x;
    const int b = blockIdx.x;
    const float* z2b = z2 + (size_t)b * (S * D);

    // P0: stage decoder weights; merge VQ partials
    for (int p = tid; p < 2048; p += 256) { dw1L[p] = dw1[p]; dw2L[p] = dw2[p]; }
    if (tid < 64) db1L[tid] = db1[tid];
    if (tid >= 64 && tid < 96) db2L[tid - 64] = db2[tid - 64];
    if (tid < 50) {
        const float2* pp = pbsv + (size_t)(b * S + tid) * NSLICE;
        float bs = INFINITY; int bv = 0x7fffffff;
#pragma unroll
        for (int j = 0; j < NSLICE; j++) {
            float2 p = pp[j];
            int v = __float_as_int(p.y);
            if (p.x < bs) { bs = p.x; bv = v; }   // ascending slice => lowest v on ties
        }
        vidL[tid] = bv;
    }
    __syncthreads();
    // P1: fetch z_emb rows
    {
        const int q = tid & 7;
#pragma unroll
        for (int it = 0; it < 2; it++) {
            int s = it * 32 + (tid >> 3);
            if (s < 50) {
                float4 e4 = *(const float4*)(embd + (size_t)vidL[s] * D + q * 4);
                zeL[s][q * 4 + 0] = e4.x; zeL[s][q * 4 + 1] = e4.y;
                zeL[s][q * 4 + 2] = e4.z; zeL[s][q * 4 + 3] = e4.w;
            }
        }
    }
    __syncthreads();
    // P2: loss partial + decoder phase A
    {
        const int q = tid & 7;
        float ls = 0.f;
#pragma unroll
        for (int it = 0; it < 2; it++) {
            int s = it * 32 + (tid >> 3);
            if (s < 50) {
                float4 x4 = *(const float4*)(z2b + s * D + q * 4);
                float d0 = x4.x - zeL[s][q * 4 + 0], d1 = x4.y - zeL[s][q * 4 + 1];
                float d2 = x4.z - zeL[s][q * 4 + 2], d3 = x4.w - zeL[s][q * 4 + 3];
                ls += d0 * d0 + d1 * d1 + d2 * d2 + d3 * d3;
            }
        }
#pragma unroll
        for (int off = 32; off > 0; off >>= 1) ls += __shfl_down(ls, off);
        if ((tid & 63) == 0) lossRed[tid >> 6] = ls;
        const int s = tid >> 3;
        if (s <= TT) {
#pragma unroll
            for (int j = 0; j < 8; j++) {
                int h = q * 8 + j;
                float a = db1L[h];
#pragma unroll
                for (int d = 0; d < 32; d++) a = fmaf(zeL[s][d], dw1L[d * 64 + h], a);
                aL[s][h] = (a >= 0.f) ? a : 0.1f * a;
            }
        }
    }
    __syncthreads();
    // P3: decoder phase B -> xsi ; block loss atomic
    if (tid == 0) atomicAdd(loss_sum, lossRed[0] + lossRed[1] + lossRed[2] + lossRed[3]);
    {
        const int s = tid >> 3, q = tid & 7;
        if (s <= TT) {
            float zr[4];
#pragma unroll
            for (int dd = 0; dd < 4; dd++) zr[dd] = db2L[q * 4 + dd];
            for (int h = 0; h < 64; h++) {
                float av = aL[s][h];
#pragma unroll
                for (int dd = 0; dd < 4; dd++) zr[dd] = fmaf(av, dw2L[h * 32 + q * 4 + dd], zr[dd]);
            }
            float4 o4 = make_float4(zr[0], zr[1], zr[2], zr[3]);
            *(float4*)&xsi[s][q * 4] = o4;
        }
    }
    __syncthreads();
    // GRU lane mapping: waves 0-1 lanes 0..95 -> GRU-i; waves 2-3 lanes 128..223 -> GRU-c
    const bool actG = (tid < 96) || (tid >= 128 && tid < 224);
    const int gru = (tid >= 128) ? 1 : 0;
    const int e = gru ? (tid - 128) : tid;
    // P4: gi precompute (wih row pinned in VGPRs)
    if (actG) {
        float wihRow[32];
        const float* wg = gru ? c_wih : i_wih;
#pragma unroll
        for (int d = 0; d < 32; d++) wihRow[d] = wg[e * 32 + d];
        const float bi = (gru ? c_bih : i_bih)[e];
        float* giP = gru ? &gic[0][0] : &gii[0][0];
        for (int s = 0; s <= TT; s++) {
            float g = bi;
            if (gru) {
                const float4* xp = (const float4*)(z2b + s * D);
#pragma unroll
                for (int k = 0; k < 8; k++) {
                    float4 xv = xp[k];
                    g = fmaf(xv.x, wihRow[4 * k + 0], g);
                    g = fmaf(xv.y, wihRow[4 * k + 1], g);
                    g = fmaf(xv.z, wihRow[4 * k + 2], g);
                    g = fmaf(xv.w, wihRow[4 * k + 3], g);
                }
            } else {
                const float4* xp = (const float4*)&xsi[s][0];
#pragma unroll
                for (int k = 0; k < 8; k++) {
                    float4 xv = xp[k];
                    g = fmaf(xv.x, wihRow[4 * k + 0], g);
                    g = fmaf(xv.y, wihRow[4 * k + 1], g);
                    g = fmaf(xv.z, wihRow[4 * k + 2], g);
                    g = fmaf(xv.w, wihRow[4 * k + 3], g);
                }
            }
            giP[s * 96 + e] = g;
        }
    }
    // pin whh row + init h
    float whhRow[32]; float bh = 0.f;
    if (actG) {
        const float* wg = gru ? c_whh : i_whh;
#pragma unroll
        for (int d = 0; d < 32; d++) whhRow[d] = wg[e * 32 + d];
        bh = (gru ? c_bhh : i_bhh)[e];
    }
    if (tid < 64) { (tid < 32 ? hI[0] : hC[0])[tid & 31] = 0.f; }
    __syncthreads();
    // P5: recurrent loop
    for (int t = 0; t <= TT; t++) {
        const int cur = t & 1;
        if (actG) {
            float g = bh;
            const float4* hp = (const float4*)(gru ? &hC[cur][0] : &hI[cur][0]);
#pragma unroll
            for (int k = 0; k < 8; k++) {
                float4 hv = hp[k];
                g = fmaf(hv.x, whhRow[4 * k + 0], g);
                g = fmaf(hv.y, whhRow[4 * k + 1], g);
                g = fmaf(hv.z, whhRow[4 * k + 2], g);
                g = fmaf(hv.w, whhRow[4 * k + 3], g);
            }
            (gru ? ghC : ghI)[e] = g;
        }
        __syncthreads();
        if (tid < 64) {
            const int g2 = tid >> 5, l = tid & 31;
            const float* giP = g2 ? &gic[t][0] : &gii[t][0];
            const float* ghP = g2 ? ghC : ghI;
            float* hP = g2 ? &hC[0][0] : &hI[0][0];
            float rr = sigmoidf_(giP[l] + ghP[l]);
            float zz = sigmoidf_(giP[l + 32] + ghP[l + 32]);
            float nn = tanhf(giP[l + 64] + rr * ghP[l + 64]);
            hP[(1 - cur) * 32 + l] = (1.f - zz) * nn + zz * hP[cur * 32 + l];
        }
        __syncthreads();
    }
    // P6: output MLPs (final h in index 1). lanes 0..31 -> i-path, 128..159 -> c-path
    {
        const bool actM = (tid < 32) || (tid >= 128 && tid < 160);
        const int g2 = (tid >= 128) ? 1 : 0;
        const int l = tid & 31;
        if (actM) {
            const float* w1 = g2 ? cm_w1 : im_w1;
            const float* b1 = g2 ? cm_b1 : im_b1;
            const float* hP = g2 ? &hC[1][0] : &hI[1][0];
            float a = b1[l];
#pragma unroll
            for (int d = 0; d < 32; d++) a = fmaf(hP[d], w1[d * 32 + l], a);
            afL[g2][l] = tanhf(a);
        }
        __syncthreads();
        if (actM) {
            const float* w2 = g2 ? cm_w2 : im_w2;
            const float* b2 = g2 ? cm_b2 : im_b2;
            float o = b2[l];
#pragma unroll
            for (int d = 0; d < 32; d++) o = fmaf(afL[g2][d], w2[d * 32 + l], o);
            (g2 ? z2fL : z1fL)[l] = o;
        }
        if (tid < 32) ocs[tid] = x1[b * 32 + tid];
    }
    __syncthreads();
    // P7: wgen  w[ly][kk] = clip(z1f.hw1) + z2f.hw2
    {
        const int kk = tid;
#pragma unroll
        for (int ly = 0; ly < LL; ly++) {
            float a = hb1[ly * 256 + kk], c = hb2[ly * 256 + kk];
            const float* h1 = hw1 + ly * 8192 + kk;
            const float* h2 = hw2 + ly * 8192 + kk;
#pragma unroll
            for (int d = 0; d < 32; d++) {
                a = fmaf(z1fL[d], h1[d * 256], a);
                c = fmaf(z2fL[d], h2[d * 256], c);
            }
            a = fminf(fmaxf(a, -NORMC), NORMC);
            wW[ly * 256 + kk] = a + c;
        }
    }
    __syncthreads();
    // P8: apply
#pragma unroll
    for (int i = 0; i < LL; i++) {
        if (tid < 16) {
            float a = lin_b[i * 16 + tid];
#pragma unroll
            for (int u = 0; u < 32; u++) a = fmaf(ocs[u], lin_w[i * 512 + u * 16 + tid], a);
            t1s[tid] = a;
        }
        __syncthreads();
        if (tid < 16) {
            float a = 0.f;
#pragma unroll
            for (int k = 0; k < 16; k++) a = fmaf(t1s[k], wW[i * 256 + k * 16 + tid], a);
            t2s[tid] = a;
        }
        __syncthreads();
        if (tid < 32) {
            float a = lout_b[i * 32 + tid];
#pragma unroll
            for (int k = 0; k < 16; k++) a = fmaf(t2s[k], lout_w[i * 512 + k * 32 + tid], a);
            ocs[tid] = a;
        }
        __syncthreads();
    }
    if (tid < 32) out[(size_t)b * 32 + tid] = ocs[tid];
    // P9: loss finalize via ticket
    if (tid == 0) {
        __threadfence();
        unsigned int old = atomicAdd(cnt, 1u);
        if (old == B - 1) {
            float tot = atomicAdd(loss_sum, 0.0f);
            out[B * UU] = tot * (1.0f / (float)(B * S * D));
        }
    }
}

extern "C" void kernel_launch(void* const* d_in, const int* in_sizes, int n_in,
                              void* d_out, int out_size, void* d_ws, size_t ws_size,
                              hipStream_t stream) {
    const float* x1     = (const float*)d_in[0];
    const float* z1     = (const float*)d_in[1];
    const float* z2     = (const float*)d_in[3];
    const float* embd   = (const float*)d_in[4];
    const float* dec_w1 = (const float*)d_in[5];
    const float* dec_b1 = (const float*)d_in[6];
    const float* dec_w2 = (const float*)d_in[7];
    const float* dec_b2 = (const float*)d_in[8];
    const float* i_wih  = (const float*)d_in[9];
    const float* i_whh  = (const float*)d_in[10];
    const float* i_bih  = (const float*)d_in[11];
    const float* i_bhh  = (const float*)d_in[12];
    const float* c_wih  = (const float*)d_in[13];
    const float* c_whh  = (const float*)d_in[14];
    const float* c_bih  = (const float*)d_in[15];
    const float* c_bhh  = (const float*)d_in[16];
    const float* im_w1  = (const float*)d_in[17];
    const float* im_b1  = (const float*)d_in[18];
    const float* im_w2  = (const float*)d_in[19];
    const float* im_b2  = (const float*)d_in[20];
    const float* cm_w1  = (const float*)d_in[21];
    const float* cm_b1  = (const float*)d_in[22];
    const float* cm_w2  = (const float*)d_in[23];
    const float* cm_b2  = (const float*)d_in[24];
    const float* hw1    = (const float*)d_in[25];
    const float* hb1    = (const float*)d_in[26];
    const float* hw2    = (const float*)d_in[27];
    const float* hb2    = (const float*)d_in[28];
    const float* lin_w  = (const float*)d_in[29];
    const float* lin_b  = (const float*)d_in[30];
    const float* lout_w = (const float*)d_in[31];
    const float* lout_b = (const float*)d_in[32];

    // workspace layout (floats)
    float* wsf      = (float*)d_ws;
    float* loss_sum = wsf;                        // [0]
    unsigned int* cnt = (unsigned int*)(wsf + 1); // [1]
    float* tn       = wsf + 64;                   // VPAD -> 10304
    float2* pbsv    = (float2*)(wsf + 10304);     // NROWS*NSLICE float2 = 512000 f -> 522304
    unsigned short* Eh = (unsigned short*)(wsf + 522304);  // VPAD*32 shorts = 163840 f -> 686144
    unsigned short* El = (unsigned short*)(wsf + 686144);  // -> 849984  (~3.4 MB)

    k_prep<<<(VPAD * 4 + 255) / 256, 256, 0, stream>>>(embd, Eh, El, tn, loss_sum, cnt);
    k_vq<<<NSLICE * NRG, 256, 0, stream>>>(z1, (const short*)Eh, (const short*)El, tn, pbsv);
    k_fused<<<B, 256, 0, stream>>>(x1, z2, embd, pbsv,
                                   dec_w1, dec_b1, dec_w2, dec_b2,
                                   i_wih, i_whh, i_bih, i_bhh,
                                   c_wih, c_whh, c_bih, c_bhh,
                                   im_w1, im_b1, im_w2, im_b2,
                                   cm_w1, cm_b1, cm_w2, cm_b2,
                                   hw1, hb1, hw2, hb2,
                                   lin_w, lin_b, lout_w, lout_b,
                                   loss_sum, cnt, (float*)d_out);
}